// Round 5
// baseline (98.713 us; speedup 1.0000x reference)
//
#include <hip/hip_runtime.h>
#include <math.h>

#define B_ 32
#define S_ 8192
#define D_ 256
#define TS 32                 // columns per tile
#define TPB 8                 // tiles per block
#define BPB (S_ / (TS * TPB)) // 32 blocks per batch row

// ws layout (floats):
//   wh    [B_*D_]        @ 0
//   sc    [B_*S_]        @ 16384
//   ml    [B_*BPB*2]     @ 278528
//   opart [B_*BPB*D_]    @ 280576   (ends 542720)

// K1: wh[b,d] = sum_e W[e,d] * h[b,e]
__global__ __launch_bounds__(256) void k_wh(const float* __restrict__ W,
                                            const float* __restrict__ h,
                                            float* __restrict__ wh) {
  const int b = blockIdx.x;
  const int d = threadIdx.x;
  __shared__ float hs[D_];
  hs[d] = h[b * D_ + d];
  __syncthreads();
  float acc = 0.f;
#pragma unroll 8
  for (int e = 0; e < D_; ++e) acc = fmaf(W[e * D_ + d], hs[e], acc);
  wh[b * D_ + d] = acc;
}

// K2: register-resident flash pass with software-pipelined double-buffer
// prefetch: tile tt+1's loads are issued before tile tt's softmax barrier so
// HBM stays busy through the (otherwise correlated-idle) softmax phase.
__global__ __launch_bounds__(256, 4) void k_fused(const float* __restrict__ cv,
                                                  const float* __restrict__ wh,
                                                  const int* __restrict__ mask,
                                                  float* __restrict__ sc,
                                                  float* __restrict__ ml,
                                                  float* __restrict__ opart) {
  __shared__ float scpart[256 * 4];   // per-thread score partial float4 (4KB)
  __shared__ float ps[TS];            // exp(score - m_new)
  __shared__ float fbox;              // per-tile rescale factor
  __shared__ float opred[TPB][256];   // o reduction scratch (8KB)

  const int b = blockIdx.y;
  const int blk = blockIdx.x;
  const int t = threadIdx.x;
  const int rg = t >> 3;              // row-group base (0..31)
  const int cq = t & 7;               // column-quad (0..7)
  const int s_base = blk * (TS * TPB);
  const float* cvb = cv + (size_t)b * D_ * S_;

  float wh8[8];
#pragma unroll
  for (int it = 0; it < 8; ++it) wh8[it] = wh[b * D_ + rg + 32 * it];

  int mbits[TPB];
  if (t < TS) {
#pragma unroll
    for (int it = 0; it < TPB; ++it)
      mbits[it] = mask[b * S_ + s_base + it * TS + t];
  }

  float o[8];
#pragma unroll
  for (int it = 0; it < 8; ++it) o[it] = 0.f;
  float mrun = -1e30f, lrun = 0.f;

  float4 vA[8], vB[8];

#define LOADT(dst, tt)                                                        \
  _Pragma("unroll")                                                           \
  for (int it = 0; it < 8; ++it)                                              \
    dst[it] = *reinterpret_cast<const float4*>(                               \
        cvb + (size_t)(rg + 32 * it) * S_ + s_base + (tt) * TS + 4 * cq);

#define STEP(vc, vl, tt, doload)                                              \
  {                                                                           \
    float4 p; p.x = 0.f; p.y = 0.f; p.z = 0.f; p.w = 0.f;                     \
    _Pragma("unroll")                                                         \
    for (int it = 0; it < 8; ++it) {                                          \
      p.x = fmaf(vc[it].x, wh8[it], p.x);                                     \
      p.y = fmaf(vc[it].y, wh8[it], p.y);                                     \
      p.z = fmaf(vc[it].z, wh8[it], p.z);                                     \
      p.w = fmaf(vc[it].w, wh8[it], p.w);                                     \
    }                                                                         \
    *reinterpret_cast<float4*>(&scpart[t * 4]) = p;                           \
    if (doload) { LOADT(vl, (tt) + 1) }                                       \
    __syncthreads(); /* B1 */                                                 \
    if (t < TS) {                                                             \
      float sv = 0.f;                                                         \
      _Pragma("unroll")                                                       \
      for (int k = 0; k < 32; ++k) sv += scpart[k * 32 + t];                  \
      if (mbits[tt] != 0) sv = -INFINITY;                                     \
      sc[(size_t)b * S_ + s_base + (tt) * TS + t] = sv;                       \
      float pm = sv;                                                          \
      _Pragma("unroll")                                                       \
      for (int off = 16; off > 0; off >>= 1)                                  \
        pm = fmaxf(pm, __shfl_xor(pm, off, 64));                              \
      const float mnew = fmaxf(fmaxf(mrun, pm), -1e30f);                      \
      const float f = __expf(mrun - mnew);                                    \
      const float e = __expf(sv - mnew);                                      \
      float pl = e;                                                           \
      _Pragma("unroll")                                                       \
      for (int off = 16; off > 0; off >>= 1) pl += __shfl_xor(pl, off, 64);   \
      lrun = lrun * f + pl;                                                   \
      mrun = mnew;                                                            \
      ps[t] = e;                                                              \
      if (t == 0) fbox = f;                                                   \
    }                                                                         \
    __syncthreads(); /* B2 */                                                 \
    {                                                                         \
      const float f = fbox;                                                   \
      const float4 p4 = *reinterpret_cast<const float4*>(&ps[4 * cq]);        \
      _Pragma("unroll")                                                       \
      for (int it = 0; it < 8; ++it) {                                        \
        const float add = vc[it].x * p4.x + vc[it].y * p4.y +                 \
                          vc[it].z * p4.z + vc[it].w * p4.w;                  \
        o[it] = fmaf(o[it], f, add);                                          \
      }                                                                       \
    }                                                                         \
  }

  LOADT(vA, 0)
  STEP(vA, vB, 0, 1)
  STEP(vB, vA, 1, 1)
  STEP(vA, vB, 2, 1)
  STEP(vB, vA, 3, 1)
  STEP(vA, vB, 4, 1)
  STEP(vB, vA, 5, 1)
  STEP(vA, vB, 6, 1)
  STEP(vB, vA, 7, 0)
#undef STEP
#undef LOADT

  // reduce o over the 8 column-quad threads per row
#pragma unroll
  for (int it = 0; it < 8; ++it) opred[it][t] = o[it];
  __syncthreads();
  float od = 0.f;
  const int k0 = 8 * (t & 31);
  const int itq = t >> 5;
#pragma unroll
  for (int c8 = 0; c8 < 8; ++c8) od += opred[itq][k0 + c8];
  opart[((size_t)b * BPB + blk) * D_ + t] = od;
  if (t == 0) {
    ml[((size_t)b * BPB + blk) * 2] = mrun;
    ml[((size_t)b * BPB + blk) * 2 + 1] = lrun;
  }
}

// K3 (combine+bcast fused): blocks [0, seqlen*B_) each write one attn output
// row (copy i, batch b), recomputing (M, invL) from the tiny ml array.
// Blocks [seqlen*B_, seqlen*B_ + seqlen*8) compute+write ctx (4 b x 256 d each).
__global__ __launch_bounds__(256) void k_out(const float* __restrict__ ml,
                                             const float* __restrict__ opart,
                                             const float* __restrict__ sc,
                                             float* __restrict__ out,
                                             int seqlen) {
  const int nAttn = seqlen * B_;
  const int id = blockIdx.x;
  const int t = threadIdx.x;
  __shared__ float sM, sI;

  if (id < nAttn) {
    const int i = id >> 5;          // copy index
    const int b = id & 31;
    if (t < 64) {
      float mval = -1e30f, lval = 0.f;
      if (t < BPB) {
        mval = ml[((size_t)b * BPB + t) * 2];
        lval = ml[((size_t)b * BPB + t) * 2 + 1];
      }
      float M = mval;
#pragma unroll
      for (int off = 32; off > 0; off >>= 1) M = fmaxf(M, __shfl_xor(M, off, 64));
      float ll = lval * __expf(mval - M);
#pragma unroll
      for (int off = 32; off > 0; off >>= 1) ll += __shfl_xor(ll, off, 64);
      if (t == 0) { sM = M; sI = 1.0f / ll; }
    }
    __syncthreads();
    const float M = sM, invL = sI;
    float4* dst = reinterpret_cast<float4*>(
        out + (size_t)seqlen * B_ * D_ + ((size_t)i * B_ + b) * S_);
    const float4* src = reinterpret_cast<const float4*>(sc + (size_t)b * S_);
#pragma unroll
    for (int j = 0; j < S_ / 4 / 256; ++j) {
      const int q = j * 256 + t;
      const float4 v = src[q];
      float4 r;
      r.x = __expf(v.x - M) * invL;
      r.y = __expf(v.y - M) * invL;
      r.z = __expf(v.z - M) * invL;
      r.w = __expf(v.w - M) * invL;
      dst[q] = r;
    }
  } else {
    const int j = id - nAttn;
    const int i = j >> 3;                    // copy index
    const int b = (j & 7) * 4 + (t >> 6);    // one wave per b
    const int lane = t & 63;
    float mval = -1e30f, lval = 0.f;
    if (lane < BPB) {
      mval = ml[((size_t)b * BPB + lane) * 2];
      lval = ml[((size_t)b * BPB + lane) * 2 + 1];
    }
    float M = mval;
#pragma unroll
    for (int off = 32; off > 0; off >>= 1) M = fmaxf(M, __shfl_xor(M, off, 64));
    float ll = lval * __expf(mval - M);
#pragma unroll
    for (int off = 32; off > 0; off >>= 1) ll += __shfl_xor(ll, off, 64);
    const float invL = 1.0f / ll;

    float4 acc; acc.x = 0.f; acc.y = 0.f; acc.z = 0.f; acc.w = 0.f;
    for (int ti = 0; ti < BPB; ++ti) {
      const float em = __expf(__shfl(mval, ti, 64) - M);
      const float4 op = *reinterpret_cast<const float4*>(
          opart + ((size_t)b * BPB + ti) * D_ + 4 * lane);
      acc.x = fmaf(op.x, em, acc.x);
      acc.y = fmaf(op.y, em, acc.y);
      acc.z = fmaf(op.z, em, acc.z);
      acc.w = fmaf(op.w, em, acc.w);
    }
    acc.x *= invL; acc.y *= invL; acc.z *= invL; acc.w *= invL;
    *reinterpret_cast<float4*>(out + ((size_t)i * B_ + b) * D_ + 4 * lane) = acc;
  }
}

extern "C" void kernel_launch(void* const* d_in, const int* in_sizes, int n_in,
                              void* d_out, int out_size, void* d_ws, size_t ws_size,
                              hipStream_t stream) {
  // inputs: 0=seqlen(1), 1=hidden(B*D), 2=contextvects(B*D*S), 3=W(D*D),
  //         4=b(D) [softmax-invariant, dropped], 5=padding_mask(B*S)
  const float* hidden = (const float*)d_in[1];
  const float* cv = (const float*)d_in[2];
  const float* W = (const float*)d_in[3];
  const int* mask = (const int*)d_in[5];

  float* ws = (float*)d_ws;
  float* wh = ws;
  float* sc = ws + 16384;
  float* ml = ws + 278528;
  float* opart = ws + 280576;

  const int seqlen = out_size / (B_ * D_ + B_ * S_);

  k_wh<<<B_, D_, 0, stream>>>(W, hidden, wh);
  k_fused<<<dim3(BPB, B_), 256, 0, stream>>>(cv, wh, mask, sc, ml, opart);
  k_out<<<seqlen * B_ + seqlen * 8, 256, 0, stream>>>(ml, opart, sc,
                                                      (float*)d_out, seqlen);
}